// Round 14
// baseline (1073.035 us; speedup 1.0000x reference)
//
#include <hip/hip_runtime.h>
#include <hip/hip_bf16.h>

// TreeHopNode: h = q - rep + (per-head MLP(sigmoid(Qh*Kh/16)*Vh)) @ Ws
// N=65536, E=1024, H=4, G=256, MLP=256. bf16 MFMA 16x16x32, f32 accum.
//
// R14 = R13 (passed, 1001us) with G1 FUSED into G23 -> gemm_g123:
// triple accumulator (Qh from qb, Kh/Vh from rb) over K=1024; epilogue
// z = sigmoid(acq*ack/16)*acv fully in-register. Kills the G1 dispatch,
// the gh buffer round-trip, and one prologue/epilogue.
//  - 2-slot LDS rotation (56KB/slice x2 = 112KB).
//  - Gate rule (from R9/R11 analysis): ALL 7 stage loads issue at MH0;
//    vmcnt(0) at MH1 -> gate distance ~1 phase (~1800cy) > HBM 900cy = cold.
//    (R11's +7% was a same-phase drain; R9's cold gates nulled.)
//  - Register budget: a-frags read one-at-a-time inside the MFMA section
//    (peak live ~= 192 acc + 24 b + 4 a + addr ~ 240 < 256).
// Ledger: RAW - gate+barrier at (s,MH1) proves slice s+1 block-wide before
// its first read at (s+1,MH0). WAR - stage target slot (s+1)&1 was last
// read in (s-1)'s MFMA sections, >=2 barriers before the stage issue.
// Tail clamps SOURCE only. mlp/F/cvt/prep unchanged from R13.

typedef __attribute__((ext_vector_type(8))) short bf16x8;
typedef __attribute__((ext_vector_type(4))) float f32x4;
typedef __attribute__((ext_vector_type(4))) short short4v;

#define AS1 __attribute__((address_space(1)))
#define AS3 __attribute__((address_space(3)))

static __device__ __forceinline__ short f2b(float x) {
  __hip_bfloat16 h = __float2bfloat16(x);
  return __builtin_bit_cast(short, h);
}
static __device__ __forceinline__ float b2f(short s) {
  unsigned u = ((unsigned)(unsigned short)s) << 16;
  return __builtin_bit_cast(float, u);
}

// ---------------- convert f32 -> bf16 (both inputs, one launch) ----------
__global__ void cvt_bf16_2(const float* __restrict__ q, const float* __restrict__ rep,
                           short* __restrict__ qb, short* __restrict__ rb, long n) {
  const float* __restrict__ in = blockIdx.z ? rep : q;
  short* __restrict__ out = blockIdx.z ? rb : qb;
  long i = ((long)blockIdx.x * blockDim.x + threadIdx.x) * 4;
  const long stride = (long)gridDim.x * blockDim.x * 4;
  for (; i < n; i += stride) {
    float4 v = *(const float4*)(in + i);
    short4v o = { f2b(v.x), f2b(v.y), f2b(v.z), f2b(v.w) };
    *(short4v*)(out + i) = o;
  }
}

// ---------------- transpose + convert weights ----------------
__global__ void prep_weights(
    const float* __restrict__ Wq, const float* __restrict__ Wk, const float* __restrict__ Wv,
    const float* __restrict__ W1, const float* __restrict__ W2, const float* __restrict__ Ws,
    short* __restrict__ wqt, short* __restrict__ wkt, short* __restrict__ wvt,
    short* __restrict__ w1t, short* __restrict__ w2t, short* __restrict__ wst)
{
  const int job = blockIdx.z;
  const float* src; short* dst; int R, C;
  if (job < 3)       { src = (job==0)?Wq:((job==1)?Wk:Wv); dst = (job==0)?wqt:((job==1)?wkt:wvt); R = 1024; C = 1024; }
  else if (job == 3) { src = Ws; dst = wst; R = 1024; C = 1024; }
  else if (job < 8)  { int h = job-4; src = W1 + h*65536; dst = w1t + h*65536; R = 256; C = 256; }
  else               { int h = job-8; src = W2 + h*65536; dst = w2t + h*65536; R = 256; C = 256; }
  const int c0 = blockIdx.x * 32, r0 = blockIdx.y * 32;
  if (c0 >= C || r0 >= R) return;
  __shared__ float t[32][33];
  for (int i = threadIdx.y; i < 32; i += 8)
    t[i][threadIdx.x] = src[(long)(r0 + i) * C + c0 + threadIdx.x];
  __syncthreads();
  for (int i = threadIdx.y; i < 32; i += 8)
    dst[(long)(c0 + i) * R + r0 + threadIdx.x] = f2b(t[threadIdx.x][i]);
}

// ---------------- 256x256-tile bf16 GEMM, 4-slot pipeline (R12) ---------
template <int KDIM, int LDA, int LDB, bool RELU, bool BIAS, bool RESID, bool SWZ>
__global__ __launch_bounds__(512, 2) void gemm_bf16(
    const short* __restrict__ A, long zsa,
    const short* __restrict__ Bt, long zsb,
    void* __restrict__ outv, long ldc, long zsc,
    const float* __restrict__ bias, long zsbias,
    const short* __restrict__ qres, const short* __restrict__ rres)
{
  __shared__ __align__(16) short lA[4 * 8192];     // 4 slots of [256][32]
  __shared__ __align__(16) short lB[4 * 8192];
  const int lane = threadIdx.x & 63, wave = threadIdx.x >> 6;
  const int wm = wave >> 2, wn = wave & 3;         // 2M x 4N wave grid
  int bx = blockIdx.x, by = blockIdx.y;
  if (SWZ) {
    const int nbx = gridDim.x;
    const int flat = by * nbx + bx;
    const int chunk = (int)(gridDim.x * gridDim.y) >> 3;
    const int fid = (flat & 7) * chunk + (flat >> 3);
    bx = fid % nbx; by = fid / nbx;
  }
  const long bm = (long)by * 256;
  const int  bn = bx * 256;
  const int  zi = blockIdx.z;

  const short* Ab = A + (long)zi * zsa + bm * LDA;
  const short* Bb = Bt + (long)zi * zsb + (long)bn * LDB;
  constexpr int NS = KDIM / 32;                    // k-slices (32 wide)
  const int g0 = lane >> 4;
  const int arow = wm * 128 + (lane & 15);
  const int bcol = wn * 64 + (lane & 15);

  const char* aP = (const char*)lA + arow * 64 + (((g0 ^ (arow >> 1)) & 3) << 4);
  const char* bP = (const char*)lB + bcol * 64 + (((g0 ^ (bcol >> 1)) & 3) << 4);

  const int rw = lane >> 2;
  const int gg = (lane & 3) ^ ((rw >> 1) & 3);
  const short* Asrc = Ab + (wave * 16 + rw) * LDA + (gg << 3);
  const short* Bsrc = Bb + (wave * 16 + rw) * LDB + (gg << 3);
  short* lAd = lA + wave * 16 * 32;
  short* lBd = lB + wave * 16 * 32;

  auto stA = [&](int slot, int s) {
    const int sc = s < NS ? s : NS - 1;            // tail: clamp SOURCE only
    const short* src = Asrc + sc * 32;
    short* d = lAd + slot * 8192;
    __builtin_amdgcn_global_load_lds((const AS1 void*)src,              (AS3 void*)d,        16, 0, 0);
    __builtin_amdgcn_global_load_lds((const AS1 void*)(src + 128*LDA),  (AS3 void*)(d+4096), 16, 0, 0);
  };
  auto stB = [&](int slot, int s) {
    const int sc = s < NS ? s : NS - 1;
    const short* src = Bsrc + sc * 32;
    short* d = lBd + slot * 8192;
    __builtin_amdgcn_global_load_lds((const AS1 void*)src,              (AS3 void*)d,        16, 0, 0);
    __builtin_amdgcn_global_load_lds((const AS1 void*)(src + 128*LDB),  (AS3 void*)(d+4096), 16, 0, 0);
  };

  stA(0, 0); stB(0, 0);
  stA(1, 1); stB(1, 1);
  stA(2, 2); stB(2, 2);
  asm volatile("s_waitcnt vmcnt(8)" ::: "memory");
  __builtin_amdgcn_s_barrier();

  f32x4 acc[8][4] = {};
  bf16x8 b[4];

#define PHASE(SLOT, MH, LOADB, STAGE_STMT, DOVM)                            \
  {                                                                         \
    if (LOADB) {                                                            \
      _Pragma("unroll")                                                     \
      for (int j = 0; j < 4; ++j)                                           \
        b[j] = *(const bf16x8*)(bP + (SLOT) * 16384 + j * 1024);            \
    }                                                                       \
    bf16x8 a[4];                                                            \
    _Pragma("unroll")                                                       \
    for (int i2 = 0; i2 < 4; ++i2)                                          \
      a[i2] = *(const bf16x8*)(aP + (SLOT) * 16384 + (MH) * 4096 + i2 * 1024); \
    STAGE_STMT;                                                             \
    if (DOVM) asm volatile("s_waitcnt vmcnt(8)" ::: "memory");              \
    asm volatile("" ::: "memory");                                          \
    __builtin_amdgcn_s_barrier();                                           \
    __builtin_amdgcn_s_setprio(1);                                          \
    _Pragma("unroll")                                                       \
    for (int i2 = 0; i2 < 4; ++i2)                                          \
      _Pragma("unroll")                                                     \
      for (int j = 0; j < 4; ++j)                                           \
        acc[(MH) * 4 + i2][j] = __builtin_amdgcn_mfma_f32_16x16x32_bf16(    \
            a[i2], b[j], acc[(MH) * 4 + i2][j], 0, 0, 0);                   \
    __builtin_amdgcn_s_setprio(0);                                          \
    asm volatile("" ::: "memory");                                          \
    __builtin_amdgcn_s_barrier();                                           \
  }

  for (int s = 0; s < NS; s += 4) {
    PHASE(0, 0, true,  stA(3, s + 3), false) PHASE(0, 1, false, stB(3, s + 3), true)
    PHASE(1, 0, true,  stA(0, s + 4), false) PHASE(1, 1, false, stB(0, s + 4), true)
    PHASE(2, 0, true,  stA(1, s + 5), false) PHASE(2, 1, false, stB(1, s + 5), true)
    PHASE(3, 0, true,  stA(2, s + 6), false) PHASE(3, 1, false, stB(2, s + 6), true)
  }
#undef PHASE

  // epilogue; C/D layout: col=lane&15, row=(lane>>4)*4+reg (m89)
  #pragma unroll
  for (int i = 0; i < 8; ++i)
    #pragma unroll
    for (int j = 0; j < 4; ++j)
      #pragma unroll
      for (int r = 0; r < 4; ++r) {
        const int rl = wm * 128 + i * 16 + ((lane >> 4) << 2) + r;
        const int cl = wn * 64 + j * 16 + (lane & 15);
        float v = acc[i][j][r];
        if (BIAS) v += bias[(long)zi * zsbias + bn + cl];
        if (RELU) v = v > 0.0f ? v : 0.0f;
        const long row = bm + rl;
        const long gi = (long)zi * zsc + row * ldc + bn + cl;
        if (RESID) {
          ((float*)outv)[gi] = b2f(qres[gi]) - b2f(rres[gi]) + v;
        } else {
          ((short*)outv)[gi] = f2b(v);
        }
      }
}

// ------- fused G1+G2+G3: z = sigmoid((q@Wq)*(rep@Wk)/16) * (rep@Wv) ------
// 256x128 tile, TRIPLE accumulators. 2-slot LDS (56KB/slice). All 7 stage
// loads issue at MH0; vmcnt(0) gate at MH1 (distance ~1 phase = cold).
// a-frags read one-at-a-time inside the MFMA section (register relief).
__global__ __launch_bounds__(512, 2) void gemm_g123(
    const short* __restrict__ qb,    // Aq: q bf16 [65536][1024]
    const short* __restrict__ rb,    // Ar: rep bf16 [65536][1024]
    const short* __restrict__ wqt,   // Bq [col][k]
    const short* __restrict__ wkt,   // Bk [col][k]
    const short* __restrict__ wvt,   // Bv [col][k]
    short* __restrict__ zb)          // z bf16 out
{
  __shared__ __align__(16) short lAq[2 * 8192];    // 32KB: 256 rows x 32k
  __shared__ __align__(16) short lAr[2 * 8192];    // 32KB
  __shared__ __align__(16) short lQ[2 * 4096];     // 16KB: 128 cols x 32k
  __shared__ __align__(16) short lK[2 * 4096];     // 16KB
  __shared__ __align__(16) short lV[2 * 4096];     // 16KB  -> 112KB total
  const int lane = threadIdx.x & 63, wave = threadIdx.x >> 6;
  const int wm = wave >> 2, wn = wave & 3;         // per-wave out: 128 x 32
  int bx = blockIdx.x, by = blockIdx.y;
  {
    const int flat = by * 8 + bx;                  // gridDim.x == 8
    const int chunk = (int)(gridDim.x * gridDim.y) >> 3;
    const int fid = (flat & 7) * chunk + (flat >> 3);
    bx = fid & 7; by = fid >> 3;
  }
  const long bm = (long)by * 256;
  const int  bn = bx * 128;

  const short* Aqb = qb + bm * 1024;
  const short* Arb = rb + bm * 1024;
  const short* Qb = wqt + (long)bn * 1024;
  const short* Kb = wkt + (long)bn * 1024;
  const short* Vb = wvt + (long)bn * 1024;
  constexpr int NS = 32;                           // K = 1024
  const int g0 = lane >> 4;
  const int arow = wm * 128 + (lane & 15);
  const int bcol = wn * 32 + (lane & 15);

  const char* aPq = (const char*)lAq + arow * 64 + (((g0 ^ (arow >> 1)) & 3) << 4);
  const char* aPr = (const char*)lAr + arow * 64 + (((g0 ^ (arow >> 1)) & 3) << 4);
  const char* qP = (const char*)lQ + bcol * 64 + (((g0 ^ (bcol >> 1)) & 3) << 4);
  const char* kP = (const char*)lK + bcol * 64 + (((g0 ^ (bcol >> 1)) & 3) << 4);
  const char* vP = (const char*)lV + bcol * 64 + (((g0 ^ (bcol >> 1)) & 3) << 4);

  const int rw = lane >> 2;
  const int gg = (lane & 3) ^ ((rw >> 1) & 3);
  const short* Aqsrc = Aqb + (wave * 16 + rw) * 1024 + (gg << 3);
  const short* Arsrc = Arb + (wave * 16 + rw) * 1024 + (gg << 3);
  const short* Qsrc = Qb + (wave * 16 + rw) * 1024 + (gg << 3);
  const short* Ksrc = Kb + (wave * 16 + rw) * 1024 + (gg << 3);
  const short* Vsrc = Vb + (wave * 16 + rw) * 1024 + (gg << 3);
  short* lAqd = lAq + wave * 16 * 32;
  short* lArd = lAr + wave * 16 * 32;
  short* lQd = lQ + wave * 16 * 32;
  short* lKd = lK + wave * 16 * 32;
  short* lVd = lV + wave * 16 * 32;

  // stage ALL of slice s into slot (7 loads/thread)
  auto stAll = [&](int slot, int s) {
    const int sc = s < NS ? s : NS - 1;            // tail: clamp SOURCE only
    const short* sq = Aqsrc + sc * 32;
    const short* sr = Arsrc + sc * 32;
    short* dq = lAqd + slot * 8192;
    short* dr = lArd + slot * 8192;
    __builtin_amdgcn_global_load_lds((const AS1 void*)sq,               (AS3 void*)dq,        16, 0, 0);
    __builtin_amdgcn_global_load_lds((const AS1 void*)(sq + 128*1024),  (AS3 void*)(dq+4096), 16, 0, 0);
    __builtin_amdgcn_global_load_lds((const AS1 void*)sr,               (AS3 void*)dr,        16, 0, 0);
    __builtin_amdgcn_global_load_lds((const AS1 void*)(sr + 128*1024),  (AS3 void*)(dr+4096), 16, 0, 0);
    __builtin_amdgcn_global_load_lds((const AS1 void*)(Qsrc + sc * 32), (AS3 void*)(lQd + slot * 4096), 16, 0, 0);
    __builtin_amdgcn_global_load_lds((const AS1 void*)(Ksrc + sc * 32), (AS3 void*)(lKd + slot * 4096), 16, 0, 0);
    __builtin_amdgcn_global_load_lds((const AS1 void*)(Vsrc + sc * 32), (AS3 void*)(lVd + slot * 4096), 16, 0, 0);
  };

  // prologue: slice 0 into slot 0; drain; barrier
  stAll(0, 0);
  asm volatile("s_waitcnt vmcnt(0)" ::: "memory");
  __builtin_amdgcn_s_barrier();

  f32x4 acq[8][2] = {};
  f32x4 ack[8][2] = {};
  f32x4 acv[8][2] = {};
  bf16x8 bq[2], bk[2], bv[2];

#define PHASEQ(SLOT, MH, LOADB, STAGE_STMT, DOVM)                           \
  {                                                                         \
    if (LOADB) {                                                            \
      _Pragma("unroll")                                                     \
      for (int j = 0; j < 2; ++j) {                                         \
        bq[j] = *(const bf16x8*)(qP + (SLOT) * 8192 + j * 1024);            \
        bk[j] = *(const bf16x8*)(kP + (SLOT) * 8192 + j * 1024);            \
        bv[j] = *(const bf16x8*)(vP + (SLOT) * 8192 + j * 1024);            \
      }                                                                     \
    }                                                                       \
    STAGE_STMT;                                                             \
    if (DOVM) asm volatile("s_waitcnt vmcnt(0)" ::: "memory");              \
    asm volatile("" ::: "memory");                                          \
    __builtin_amdgcn_s_barrier();                                           \
    __builtin_amdgcn_s_setprio(1);                                          \
    _Pragma("unroll")                                                       \
    for (int i2 = 0; i2 < 4; ++i2) {                                        \
      const bf16x8 aq = *(const bf16x8*)(aPq + (SLOT) * 16384 + (MH) * 4096 + i2 * 1024); \
      _Pragma("unroll")                                                     \
      for (int j = 0; j < 2; ++j)                                           \
        acq[(MH) * 4 + i2][j] = __builtin_amdgcn_mfma_f32_16x16x32_bf16(    \
            aq, bq[j], acq[(MH) * 4 + i2][j], 0, 0, 0);                     \
    }                                                                       \
    _Pragma("unroll")                                                       \
    for (int i2 = 0; i2 < 4; ++i2) {                                        \
      const bf16x8 ar = *(const bf16x8*)(aPr + (SLOT) * 16384 + (MH) * 4096 + i2 * 1024); \
      _Pragma("unroll")                                                     \
      for (int j = 0; j < 2; ++j) {                                         \
        ack[(MH) * 4 + i2][j] = __builtin_amdgcn_mfma_f32_16x16x32_bf16(    \
            ar, bk[j], ack[(MH) * 4 + i2][j], 0, 0, 0);                     \
        acv[(MH) * 4 + i2][j] = __builtin_amdgcn_mfma_f32_16x16x32_bf16(    \
            ar, bv[j], acv[(MH) * 4 + i2][j], 0, 0, 0);                     \
      }                                                                     \
    }                                                                       \
    __builtin_amdgcn_s_setprio(0);                                          \
    asm volatile("" ::: "memory");                                          \
    __builtin_amdgcn_s_barrier();                                           \
  }

  for (int s = 0; s < NS; s += 2) {
    PHASEQ(0, 0, true,  stAll(1, s + 1), false)
    PHASEQ(0, 1, false, {}, true)
    PHASEQ(1, 0, true,  stAll(0, s + 2), false)
    PHASEQ(1, 1, false, {}, true)
  }
#undef PHASEQ

  // epilogue: z = sigmoid(Qh * Kh / 16) * Vh, all from registers
  #pragma unroll
  for (int i = 0; i < 8; ++i)
    #pragma unroll
    for (int j = 0; j < 2; ++j)
      #pragma unroll
      for (int r = 0; r < 4; ++r) {
        const int rl = wm * 128 + i * 16 + ((lane >> 4) << 2) + r;
        const int cl = wn * 32 + j * 16 + (lane & 15);
        const long gi = (bm + rl) * 1024 + bn + cl;
        const float x = acq[i][j][r] * ack[i][j][r] * 0.0625f;
        const float gate = 1.0f / (1.0f + __expf(-x));
        zb[gi] = f2b(gate * acv[i][j][r]);
      }
}

// ------------- fused MLP: ug = relu(z_h @ W1_h + b1) @ W2_h + b2 (R13) ---
__global__ __launch_bounds__(512) void gemm_mlp(
    const short* __restrict__ zb, const short* __restrict__ w1t,
    const short* __restrict__ w2t, const float* __restrict__ b1,
    const float* __restrict__ b2, short* __restrict__ ug)
{
  __shared__ __align__(16) char smem[163840];
  short* lA = (short*)smem;                        // pass1: 4 x 16KB
  short* lB = (short*)(smem + 65536);              // pass1: 4 x 16KB
  short* stash = (short*)smem;                     // h1: 128KB (after pass1)
  short* w2b = (short*)(smem + 131072);            // pass2 B: 2 x 16KB

  const int lane = threadIdx.x & 63, wave = threadIdx.x >> 6;
  const int wm = wave >> 2, wn = wave & 3;
  const long bm = (long)blockIdx.y * 256;
  const int head = blockIdx.z;

  const int g0 = lane >> 4;
  const int arow = wm * 128 + (lane & 15);
  const int bcol = wn * 64 + (lane & 15);
  const int rw = lane >> 2;
  const int gg = (lane & 3) ^ ((rw >> 1) & 3);

  // ---------- pass 1: h1 = relu(z_h @ W1_h + b1) ----------
  {
    const short* Ab = zb + bm * 1024 + head * 256;
    const short* Bb = w1t + head * 65536;
    const char* aP = (const char*)lA + arow * 64 + (((g0 ^ (arow >> 1)) & 3) << 4);
    const char* bP = (const char*)lB + bcol * 64 + (((g0 ^ (bcol >> 1)) & 3) << 4);
    const short* Asrc = Ab + (wave * 16 + rw) * 1024 + (gg << 3);
    const short* Bsrc = Bb + (wave * 16 + rw) * 256 + (gg << 3);
    short* lAd = lA + wave * 16 * 32;
    short* lBd = lB + wave * 16 * 32;

    auto stA = [&](int slot, int s) {
      const int sc = s < 8 ? s : 7;
      const short* src = Asrc + sc * 32;
      short* d = lAd + slot * 8192;
      __builtin_amdgcn_global_load_lds((const AS1 void*)src,              (AS3 void*)d,        16, 0, 0);
      __builtin_amdgcn_global_load_lds((const AS1 void*)(src + 128*1024), (AS3 void*)(d+4096), 16, 0, 0);
    };
    auto stB = [&](int slot, int s) {
      const int sc = s < 8 ? s : 7;
      const short* src = Bsrc + sc * 32;
      short* d = lBd + slot * 8192;
      __builtin_amdgcn_global_load_lds((const AS1 void*)src,              (AS3 void*)d,        16, 0, 0);
      __builtin_amdgcn_global_load_lds((const AS1 void*)(src + 128*256),  (AS3 void*)(d+4096), 16, 0, 0);
    };

    stA(0, 0); stB(0, 0);
    stA(1, 1); stB(1, 1);
    stA(2, 2); stB(2, 2);
    asm volatile("s_waitcnt vmcnt(8)" ::: "memory");
    __builtin_amdgcn_s_barrier();

    f32x4 acc[8][4] = {};
    bf16x8 b[4];

#define PHASE1(SLOT, MH, LOADB, STAGE_STMT, DOVM)                           \
    {                                                                       \
      if (LOADB) {                                                          \
        _Pragma("unroll")                                                   \
        for (int j = 0; j < 4; ++j)                                         \
          b[j] = *(const bf16x8*)(bP + (SLOT) * 16384 + j * 1024);          \
      }                                                                     \
      bf16x8 a[4];                                                          \
      _Pragma("unroll")                                                     \
      for (int i2 = 0; i2 < 4; ++i2)                                        \
        a[i2] = *(const bf16x8*)(aP + (SLOT) * 16384 + (MH) * 4096 + i2 * 1024); \
      STAGE_STMT;                                                           \
      if (DOVM) asm volatile("s_waitcnt vmcnt(8)" ::: "memory");            \
      asm volatile("" ::: "memory");                                        \
      __builtin_amdgcn_s_barrier();                                         \
      __builtin_amdgcn_s_setprio(1);                                        \
      _Pragma("unroll")                                                     \
      for (int i2 = 0; i2 < 4; ++i2)                                        \
        _Pragma("unroll")                                                   \
        for (int j = 0; j < 4; ++j)                                         \
          acc[(MH) * 4 + i2][j] = __builtin_amdgcn_mfma_f32_16x16x32_bf16(  \
              a[i2], b[j], acc[(MH) * 4 + i2][j], 0, 0, 0);                 \
      __builtin_amdgcn_s_setprio(0);                                        \
      asm volatile("" ::: "memory");                                        \
      __builtin_amdgcn_s_barrier();                                         \
    }

    for (int s = 0; s < 8; s += 4) {
      PHASE1(0, 0, true,  stA(3, s + 3), false) PHASE1(0, 1, false, stB(3, s + 3), true)
      PHASE1(1, 0, true,  stA(0, s + 4), false) PHASE1(1, 1, false, stB(0, s + 4), true)
      PHASE1(2, 0, true,  stA(1, s + 5), false) PHASE1(2, 1, false, stB(1, s + 5), true)
      PHASE1(3, 0, true,  stA(2, s + 6), false) PHASE1(3, 1, false, stB(2, s + 6), true)
    }
#undef PHASE1

    __syncthreads();     // all pass-1 LDS reads done before stash overwrite
    #pragma unroll
    for (int i = 0; i < 8; ++i)
      #pragma unroll
      for (int j = 0; j < 4; ++j)
        #pragma unroll
        for (int r = 0; r < 4; ++r) {
          const int rl = wm * 128 + i * 16 + ((lane >> 4) << 2) + r;
          const int cl = wn * 64 + j * 16 + (lane & 15);
          float v = acc[i][j][r] + b1[head * 256 + cl];
          v = v > 0.0f ? v : 0.0f;
          stash[rl * 256 + ((((cl >> 3) ^ rl) & 31) << 3) + (cl & 7)] = f2b(v);
        }
    __syncthreads();     // stash complete before pass-2 reads
  }

  // ---------- pass 2: ug = h1 @ W2_h + b2 ----------
  {
    const short* Wb = w2t + head * 65536;
    const short* Bsrc2 = Wb + (wave * 16 + rw) * 256 + (gg << 3);
    short* lBd2 = w2b + wave * 16 * 32;
    const char* b2P = (const char*)w2b + bcol * 64 + (((g0 ^ (bcol >> 1)) & 3) << 4);

    auto stW = [&](int slot, int s) {
      const int sc = s < 8 ? s : 7;
      const short* src = Bsrc2 + sc * 32;
      short* d = lBd2 + slot * 8192;
      __builtin_amdgcn_global_load_lds((const AS1 void*)src,             (AS3 void*)d,        16, 0, 0);
      __builtin_amdgcn_global_load_lds((const AS1 void*)(src + 128*256), (AS3 void*)(d+4096), 16, 0, 0);
    };

    stW(0, 0);
    asm volatile("s_waitcnt vmcnt(0)" ::: "memory");
    __builtin_amdgcn_s_barrier();

    f32x4 acc2[8][4] = {};
    bf16x8 br[4];

    for (int s = 0; s < 8; ++s) {
      const int sl = s & 1;
      const int ks = s * 4 + g0;       // 16B k-slot index in stash

#define PHASE2(MH, LOADB, STAGE_STMT, DOVM)                                 \
      {                                                                     \
        if (LOADB) {                                                        \
          _Pragma("unroll")                                                 \
          for (int j = 0; j < 4; ++j)                                       \
            br[j] = *(const bf16x8*)(b2P + sl * 16384 + j * 1024);          \
        }                                                                   \
        bf16x8 a[4];                                                        \
        _Pragma("unroll")                                                   \
        for (int i2 = 0; i2 < 4; ++i2) {                                    \
          const int row = arow + (MH) * 64 + i2 * 16;                       \
          a[i2] = *(const bf16x8*)(stash + row * 256 + (((ks ^ row) & 31) << 3)); \
        }                                                                   \
        STAGE_STMT;                                                         \
        if (DOVM) asm volatile("s_waitcnt vmcnt(0)" ::: "memory");          \
        asm volatile("" ::: "memory");                                      \
        __builtin_amdgcn_s_barrier();                                       \
        __builtin_amdgcn_s_setprio(1);                                      \
        _Pragma("unroll")                                                   \
        for (int i2 = 0; i2 < 4; ++i2)                                      \
          _Pragma("unroll")                                                 \
          for (int j = 0; j < 4; ++j)                                       \
            acc2[(MH) * 4 + i2][j] = __builtin_amdgcn_mfma_f32_16x16x32_bf16( \
                a[i2], br[j], acc2[(MH) * 4 + i2][j], 0, 0, 0);             \
        __builtin_amdgcn_s_setprio(0);                                      \
        asm volatile("" ::: "memory");                                      \
        __builtin_amdgcn_s_barrier();                                       \
      }

      PHASE2(0, true,  stW(sl ^ 1, s + 1), false)
      PHASE2(1, false, {}, true)
#undef PHASE2
    }

    #pragma unroll
    for (int i = 0; i < 8; ++i)
      #pragma unroll
      for (int j = 0; j < 4; ++j)
        #pragma unroll
        for (int r = 0; r < 4; ++r) {
          const int rl = wm * 128 + i * 16 + ((lane >> 4) << 2) + r;
          const int cl = wn * 64 + j * 16 + (lane & 15);
          const float v = acc2[i][j][r] + b2[head * 256 + cl];
          ug[(bm + rl) * 1024 + head * 256 + cl] = f2b(v);
        }
  }
}

extern "C" void kernel_launch(void* const* d_in, const int* in_sizes, int n_in,
                              void* d_out, int out_size, void* d_ws, size_t ws_size,
                              hipStream_t stream) {
  const float* q   = (const float*)d_in[0];
  const float* rep = (const float*)d_in[1];
  const float* Wq  = (const float*)d_in[2];
  const float* Wk  = (const float*)d_in[3];
  const float* Wv  = (const float*)d_in[4];
  const float* W1  = (const float*)d_in[5];
  const float* b1  = (const float*)d_in[6];
  const float* W2  = (const float*)d_in[7];
  const float* b2  = (const float*)d_in[8];
  const float* Ws  = (const float*)d_in[9];
  float* out = (float*)d_out;

  const long NE = 67108864L;   // 65536 * 1024
  char* ws = (char*)d_ws;
  // 4 x 128 MiB slots:
  //   s0: qb (cvt..F)   s1: rb (cvt..F)
  //   s2: ug (mlp..F)   s3: zb (g123..mlp)
  short* qb  = (short*)(ws);
  short* rb  = (short*)(ws + NE * 2);
  short* ugb = (short*)(ws + NE * 4);
  short* zb  = (short*)(ws + NE * 6);
  char*  wp  = ws + NE * 8;
  short* wqt = (short*)(wp);                 // 2 MiB each
  short* wkt = (short*)(wp + 2097152);
  short* wvt = (short*)(wp + 4194304);
  short* wst = (short*)(wp + 6291456);
  short* w1t = (short*)(wp + 8388608);       // 512 KiB
  short* w2t = (short*)(wp + 8912896);       // 512 KiB

  cvt_bf16_2<<<dim3(2048, 1, 2), 256, 0, stream>>>(q, rep, qb, rb, NE);
  prep_weights<<<dim3(32, 32, 12), dim3(32, 8), 0, stream>>>(
      Wq, Wk, Wv, W1, W2, Ws, wqt, wkt, wvt, w1t, w2t, wst);

  // g123: z = sigmoid((q@Wq) * (rep@Wk) / 16) * (rep@Wv)  -> zb
  gemm_g123<<<dim3(8, 256), 512, 0, stream>>>(qb, rb, wqt, wkt, wvt, zb);
  // fused MLP: ug = relu(z@W1+b1)@W2+b2  (h1 never leaves LDS)
  gemm_mlp<<<dim3(1, 256, 4), 512, 0, stream>>>(zb, w1t, w2t, b1, b2, ugb);
  // F: out = (q - rep) + ug @ Ws   (residual from bf16 qb/rb)
  gemm_bf16<1024, 1024, 1024, false, false, true, true><<<dim3(4, 256), 512, 0, stream>>>(
      ugb, 0, wst, 0, out, 1024, 0, nullptr, 0, qb, rb);
}